// Round 8
// baseline (44528.467 us; speedup 1.0000x reference)
//
#include <hip/hip_runtime.h>
#include <cstdint>
#include <cstddef>

// 4-layer projected LSTM. B=64 T=256 D=512 H=1024 P=256. fp32 in/out.
// Split-bf16 (hi+lo) MFMA operands, 3 chains (hh/hl/lh) per product.
//
// Round-8: round-7's 1-barrier/step composed-weight algorithm
//   ( g_t = W_ih x_t + (W_hh·W_hr) h_{t-1} + b ; y[t-1] lagged proj )
// rebuilt inside PROVEN resource envelopes after r7's silent launch failure
// (absmax == empty-stub value => kernel never ran; r7 had 141,952 B LDS and
// a 25.8 MB ws need, both past the proven 109,056 B / 18.09 MB):
//   - LDS 108,672 B: Wcomb-hi (66K) + packed input weights (33K) + sG/sRed.
//   - Wcomb-lo lives in 256 VGPRs/thread (64 x short8 B-frags), filled per
//     layer via 2-pass LDS-scratch redistribution. __launch_bounds__(128,1).
//   - Workspace 16.6 MB: [cnt 4K][hA 288K][hB 288K][Y 16M]. No fallbacks.
//   - Cooperative launch error now CHECKED; plain launch fallback (barrier
//     is hand-rolled; 128 WGs <= 256 CUs are co-resident either way).
// Epochs: 4*(256+1) = 1028. h ping-pongs across 2 sc1 buffers; Y in-place
// (sc1 writes leave no stale L2 copy; cached reads fenced once per layer).

#define B_ 64
#define T_ 256
#define D_ 512
#define H_ 1024
#define P_ 256
#define NWG 128
#define NTHR 128
#define UPW 8
#define WCSTR 1032     // Wcomb-hi LDS row stride (shorts): 1024+8, 16B-aligned
#define WPSTR 520      // scratch/input-weight row stride in shorts (260 u32)
#define HROWS 72       // h rows: 64 + 8 pad (proj reads 16-row tiles)

using short8  = __attribute__((ext_vector_type(8))) short;
using f32x16  = __attribute__((ext_vector_type(16))) float;
using f32x4   = __attribute__((ext_vector_type(4))) float;

#define MFMA32(a, b, c) __builtin_amdgcn_mfma_f32_32x32x16_bf16(a, b, c, 0, 0, 0)
#define MFMA16(a, b, c) __builtin_amdgcn_mfma_f32_16x16x32_bf16(a, b, c, 0, 0, 0)

__device__ inline float bf2f(short s) {
  unsigned u = ((unsigned)(unsigned short)s) << 16;
  return __builtin_bit_cast(float, u);
}
__device__ inline unsigned short f2bf(float f) {
  unsigned u = __builtin_bit_cast(unsigned, f);
  u += 0x7fffu + ((u >> 16) & 1u);   // RTNE
  return (unsigned short)(u >> 16);
}
__device__ inline void split1(float v, short& hi, short& lo) {
  unsigned short h = f2bf(v);
  hi = (short)h;
  lo = (short)f2bf(v - bf2f((short)h));
}
__device__ inline unsigned packf(float v) {
  short h, l;
  split1(v, h, l);
  return (unsigned)(unsigned short)h | ((unsigned)(unsigned short)l << 16);
}
__device__ inline void split8(const float* p, short8& hi, short8& lo) {
  float4 a = *(const float4*)p;
  float4 b = *(const float4*)(p + 4);
  float v[8] = {a.x, a.y, a.z, a.w, b.x, b.y, b.z, b.w};
#pragma unroll
  for (int i = 0; i < 8; ++i) {
    short h, l;
    split1(v[i], h, l);
    hi[i] = h; lo[i] = l;
  }
}
// 8 packed elems, normal vector loads (global cached or LDS)
__device__ inline void unpack_c8(const unsigned* p, short8& hi, short8& lo) {
  uint4 a = *(const uint4*)p;
  uint4 b = *(const uint4*)(p + 4);
  unsigned w[8] = {a.x, a.y, a.z, a.w, b.x, b.y, b.z, b.w};
#pragma unroll
  for (int i = 0; i < 8; ++i) {
    hi[i] = (short)(w[i] & 0xffff);
    lo[i] = (short)(w[i] >> 16);
  }
}
// 8 packed elems via agent-coherent (L2-bypassing) loads: per-step mutable h
__device__ inline void unpack_a8(const unsigned* p, short8& hi, short8& lo) {
#pragma unroll
  for (int i = 0; i < 4; ++i) {
    unsigned long long v = __hip_atomic_load((const unsigned long long*)p + i,
                                             __ATOMIC_RELAXED, __HIP_MEMORY_SCOPE_AGENT);
    unsigned w0 = (unsigned)v, w1 = (unsigned)(v >> 32);
    hi[2 * i]     = (short)(w0 & 0xffff);
    lo[2 * i]     = (short)(w0 >> 16);
    hi[2 * i + 1] = (short)(w1 & 0xffff);
    lo[2 * i + 1] = (short)(w1 >> 16);
  }
}
__device__ inline float sigm(float x)   { return 1.f / (1.f + __expf(-x)); }
__device__ inline float tanh_f(float x) { return 1.f - 2.f / (__expf(2.f * x) + 1.f); }

// Striped fence-free grid barrier (round-6 proven): 32 counters, 64B apart.
#define NCNT 32
__device__ inline void gbar(unsigned* cnt, unsigned target) {
  __syncthreads();   // drains vmcnt: all sc1 stores globally visible
  if (threadIdx.x == 0) {
    __hip_atomic_fetch_add(&cnt[(blockIdx.x & (NCNT - 1)) * 16], 1u,
                           __ATOMIC_RELAXED, __HIP_MEMORY_SCOPE_AGENT);
    for (;;) {
      unsigned s = 0;
#pragma unroll
      for (int i = 0; i < NCNT; ++i)
        s += __hip_atomic_load(&cnt[i * 16], __ATOMIC_RELAXED,
                               __HIP_MEMORY_SCOPE_AGENT);
      if (s >= target) break;
      __builtin_amdgcn_s_sleep(2);
    }
  }
  __syncthreads();
}

// Lagged projection: y[tw] = h @ Whr^T, one 8x16 tile per WG, K split by wave.
__device__ inline void proj_tile(const unsigned* hSrc, const float* Whr,
                                 unsigned* Y, float* out, float* sRed,
                                 int tw, bool doOut,
                                 int wg, int lane, int wave) {
  const int m0  = (wg >> 4) * 8;
  const int n0  = (wg & 15) * 16;
  const int l16 = lane & 15;
  const int kh2 = (lane >> 4) * 8 + wave * 512;
  const unsigned* ahp = hSrc + (size_t)(m0 + l16) * H_ + kh2;   // sc1
  const float*    bwf = Whr + (size_t)(n0 + l16) * H_ + kh2;    // cached
  f32x4 phh = {}, phl = {}, plh = {};
#pragma unroll 4
  for (int k0 = 0; k0 < 512; k0 += 32) {
    short8 Ah, Al, Bh, Bl;
    unpack_a8(ahp + k0, Ah, Al);
    split8(bwf + k0, Bh, Bl);
    phh = MFMA16(Ah, Bh, phh);
    phl = MFMA16(Ah, Bl, phl);
    plh = MFMA16(Al, Bh, plh);
  }
  f32x4 a4;
#pragma unroll
  for (int r = 0; r < 4; ++r) a4[r] = phh[r] + phl[r] + plh[r];
  if (wave == 1) *(f32x4*)&sRed[lane * 4] = a4;
  __syncthreads();
  if (wave == 0) {
    f32x4 o = *(const f32x4*)&sRed[lane * 4];
#pragma unroll
    for (int r = 0; r < 4; ++r) {
      int row = (lane >> 4) * 4 + r;          // 0..15; keep 0..7
      if (row < 8) {
        int mm  = m0 + row;
        int col = n0 + l16;
        float v = a4[r] + o[r];
        __hip_atomic_store(&Y[((size_t)tw * B_ + mm) * P_ + col], packf(v),
                           __ATOMIC_RELAXED, __HIP_MEMORY_SCOPE_AGENT);
        if (doOut) out[mm * P_ + col] = v;
      }
    }
  }
  __syncthreads();
}

__global__ __launch_bounds__(NTHR, 1) void lstm_kernel(
    const float* __restrict__ x,
    const float* __restrict__ Wih0, const float* __restrict__ Whh0,
    const float* __restrict__ bih0, const float* __restrict__ bhh0,
    const float* __restrict__ Whr0,
    const float* __restrict__ Wihs, const float* __restrict__ Whhs,
    const float* __restrict__ bihs, const float* __restrict__ bhhs,
    const float* __restrict__ Whrs,
    float* __restrict__ out,
    unsigned* __restrict__ Y,
    unsigned* __restrict__ hA, unsigned* __restrict__ hB,
    unsigned* __restrict__ cnt)
{
  __shared__ __align__(16) short    sWcH[32 * WCSTR];  // 66,048 B Wcomb hi
  __shared__ __align__(16) unsigned sWiP[32 * 260];    // 33,280 B in-wgt packed / init scratch
  __shared__ __align__(16) float    sG[64 * 32];       //  8,192 B
  __shared__ float sBias[32];
  __shared__ float sRed[64 * 4];                       //  1,024 B
  // total 108,672 B  (<= 109,056 proven launchable)

  const int tid  = threadIdx.x;
  const int wg   = blockIdx.x;
  const int lane = tid & 63;
  const int wave = tid >> 6;
  unsigned ep = 0;

  // mfma_32x32x16 geometry: A m=lane&31 (+wave*32), k=(lane>>5)*8+j;
  // B n=lane&31; D col=lane&31, row=(reg&3)+8*(reg>>2)+4*(lane>>5).
  const int m1  = wave * 32 + (lane & 31);  // batch row
  const int n1  = lane & 31;                // local gate row
  const int kh1 = (lane >> 5) * 8;
  const int Rrow = (n1 & 3) * H_ + wg * UPW + (n1 >> 2);  // global gate row

  short8 wlo[64];   // Wcomb-lo B-fragments (256 VGPRs), refilled per layer

  for (int l = 0; l < 4; ++l) {
    const int K1 = (l == 0) ? D_ : P_;
    const float* Wih = (l == 0) ? Wih0 : Wihs + (size_t)(l - 1) * 4096 * 256;
    const float* Whh = (l == 0) ? Whh0 : Whhs + (size_t)(l - 1) * 4096 * 256;
    const float* bih = (l == 0) ? bih0 : bihs + (size_t)(l - 1) * 4096;
    const float* bhh = (l == 0) ? bhh0 : bhhs + (size_t)(l - 1) * 4096;
    const float* Whr = (l == 0) ? Whr0 : Whrs + (size_t)(l - 1) * 256 * 1024;

    // Per-layer full fence: invalidates stale cached Y lines (sc1-overwritten
    // by the previous layer / previous graph replay). r5-proven scheme.
    __threadfence();

    // ---- Wcomb = W_hh·W_hr for this WG's 32 gate rows.
    //      hi -> sWcH; lo -> wlo registers via 2-pass scratch redistribution.
    {
      short* scratch = (short*)sWiP;
      for (int pass = 0; pass < 2; ++pass) {
        for (int c = 0; c < 16; ++c) {
          if (wave == (c & 1)) {          // alternate chunk ownership
            const int kbase = (pass * 16 + c) * 32;
            f32x16 chh = {}, chl = {}, clh = {};
            for (int p0 = 0; p0 < P_; p0 += 16) {
              short8 Ah, Al;
              split8(Whh + (size_t)Rrow * P_ + p0 + kh1, Ah, Al);
              short8 Bh, Bl;
#pragma unroll
              for (int j = 0; j < 8; ++j) {
                short h2, l2;
                split1(Whr[(size_t)(p0 + kh1 + j) * H_ + kbase + n1], h2, l2);
                Bh[j] = h2; Bl[j] = l2;
              }
              chh = MFMA32(Ah, Bh, chh);
              chl = MFMA32(Ah, Bl, chl);
              clh = MFMA32(Al, Bh, clh);
            }
#pragma unroll
            for (int r = 0; r < 16; ++r) {
              int mrow = (r & 3) + 8 * (r >> 2) + 4 * (lane >> 5);
              short h2, l2;
              split1(chh[r] + chl[r] + clh[r], h2, l2);
              sWcH[mrow * WCSTR + kbase + n1] = h2;
              scratch[mrow * WPSTR + c * 32 + n1] = l2;
            }
          }
        }
        __syncthreads();
        if (pass == 0) {
#pragma unroll
          for (int kb = 0; kb < 32; ++kb)
            wlo[kb] = *(const short8*)&scratch[n1 * WPSTR + kb * 16 + kh1];
        } else {
#pragma unroll
          for (int kb = 0; kb < 32; ++kb)
            wlo[32 + kb] = *(const short8*)&scratch[n1 * WPSTR + kb * 16 + kh1];
        }
        __syncthreads();
      }
    }

    // ---- stage packed input weights (layers 1-3; K=256) + bias ----
    if (l > 0) {
      for (int c = tid; c < 32 * 32; c += NTHR) {   // 32 rows x 32 chunks of 8
        int r = c >> 5;
        int k = (c & 31) * 8;
        int R = (r & 3) * H_ + wg * UPW + (r >> 2);
        short8 hi, lo;
        split8(Wih + (size_t)R * P_ + k, hi, lo);
#pragma unroll
        for (int i = 0; i < 8; ++i)
          sWiP[r * 260 + k + i] = (unsigned)(unsigned short)hi[i] |
                                  ((unsigned)(unsigned short)lo[i] << 16);
      }
    }
    if (tid < 32) {
      int r = tid;
      int R = (r & 3) * H_ + wg * UPW + (r >> 2);
      sBias[r] = bih[R] + bhh[R];
    }
    __syncthreads();

    float cs0 = 0.f, cs1 = 0.f, cs2 = 0.f, cs3 = 0.f;

    for (int t = 0; t < T_; ++t) {
      const unsigned* hr = (t & 1) ? hA : hB;   // h[t-1]
      unsigned*       hw = (t & 1) ? hB : hA;   // h[t]

      // ===== gates: input part + composed recurrent part, 3 chains =====
      f32x16 ahh = {}, ahl = {}, alh = {};
      if (l == 0) {
        const float* axf = x + ((size_t)m1 * T_ + t) * D_ + kh1;
        const float* wif = Wih + (size_t)Rrow * D_ + kh1;   // L2-warm fp32
#pragma unroll 4
        for (int k0 = 0; k0 < D_; k0 += 16) {
          short8 Ah, Al, Bh, Bl;
          split8(axf + k0, Ah, Al);
          split8(wif + k0, Bh, Bl);
          ahh = MFMA32(Ah, Bh, ahh);
          ahl = MFMA32(Ah, Bl, ahl);
          alh = MFMA32(Al, Bh, alh);
        }
      } else {
        const unsigned* ypi = Y + ((size_t)t * B_ + m1) * P_ + kh1;  // cached
#pragma unroll 4
        for (int k0 = 0; k0 < P_; k0 += 16) {
          short8 Ah, Al, Bh, Bl;
          unpack_c8(ypi + k0, Ah, Al);
          unpack_c8(&sWiP[n1 * 260 + kh1 + k0], Bh, Bl);
          ahh = MFMA32(Ah, Bh, ahh);
          ahl = MFMA32(Ah, Bl, ahl);
          alh = MFMA32(Al, Bh, alh);
        }
      }
      if (t > 0) {
        const unsigned* hp = hr + (size_t)m1 * H_ + kh1;             // sc1
        const short* wch = &sWcH[n1 * WCSTR + kh1];
#pragma unroll
        for (int kb = 0; kb < 64; ++kb) {     // FULL unroll: wlo[] in VGPRs
          short8 Ah, Al;
          unpack_a8(hp + kb * 16, Ah, Al);
          short8 Bh = *(const short8*)(wch + kb * 16);
          ahh = MFMA32(Ah, Bh, ahh);
          ahl = MFMA32(Ah, wlo[kb], ahl);
          alh = MFMA32(Al, Bh, alh);
        }
      }
#pragma unroll
      for (int r = 0; r < 16; ++r) {
        int mrow = (r & 3) + 8 * (r >> 2) + 4 * (lane >> 5) + wave * 32;
        sG[mrow * 32 + n1] = ahh[r] + ahl[r] + alh[r];
      }
      __syncthreads();
      {
        const int b  = tid >> 1;
        const int u4 = (tid & 1) * 4;
        const float* gp = &sG[b * 32];
        float cr[4] = {cs0, cs1, cs2, cs3};
        unsigned pw[4];
#pragma unroll
        for (int j = 0; j < 4; ++j) {
          int u = u4 + j;
          float ii = sigm(gp[u * 4 + 0] + sBias[u * 4 + 0]);
          float ff = sigm(gp[u * 4 + 1] + sBias[u * 4 + 1]);
          float gg = tanh_f(gp[u * 4 + 2] + sBias[u * 4 + 2]);
          float oo = sigm(gp[u * 4 + 3] + sBias[u * 4 + 3]);
          float cv = ff * cr[j] + ii * gg;
          cr[j] = cv;
          pw[j] = packf(oo * tanh_f(cv));
        }
        cs0 = cr[0]; cs1 = cr[1]; cs2 = cr[2]; cs3 = cr[3];
        size_t ho = (size_t)b * H_ + wg * UPW + u4;
        unsigned long long q0 = (unsigned long long)pw[0] | ((unsigned long long)pw[1] << 32);
        unsigned long long q1 = (unsigned long long)pw[2] | ((unsigned long long)pw[3] << 32);
        __hip_atomic_store((unsigned long long*)&hw[ho], q0,
                           __ATOMIC_RELAXED, __HIP_MEMORY_SCOPE_AGENT);
        __hip_atomic_store((unsigned long long*)&hw[ho + 2], q1,
                           __ATOMIC_RELAXED, __HIP_MEMORY_SCOPE_AGENT);
      }

      // ===== lagged projection y[t-1] = h[t-1] @ Whr^T (off crit. path) ====
      if (t > 0 && l < 3)
        proj_tile(hr, Whr, Y, out, sRed, t - 1, false, wg, lane, wave);

      ep++; gbar(cnt, NWG * ep);   // h[t] visible to all for step t+1
    }

    // ===== epilogue: y[T-1]; layer 3 also writes the fp32 output ====
    {
      const unsigned* hLast = ((T_ - 1) & 1) ? hB : hA;
      proj_tile(hLast, Whr, Y, out, sRed, T_ - 1, (l == 3), wg, lane, wave);
      ep++; gbar(cnt, NWG * ep);
    }
  }
}

extern "C" void kernel_launch(void* const* d_in, const int* in_sizes, int n_in,
                              void* d_out, int out_size, void* d_ws, size_t ws_size,
                              hipStream_t stream) {
  const float* x    = (const float*)d_in[0];
  const float* Wih0 = (const float*)d_in[1];
  const float* Whh0 = (const float*)d_in[2];
  const float* bih0 = (const float*)d_in[3];
  const float* bhh0 = (const float*)d_in[4];
  const float* Whr0 = (const float*)d_in[5];
  const float* Wihs = (const float*)d_in[6];
  const float* Whhs = (const float*)d_in[7];
  const float* bihs = (const float*)d_in[8];
  const float* bhhs = (const float*)d_in[9];
  const float* Whrs = (const float*)d_in[10];
  float* out = (float*)d_out;

  char* ws = (char*)d_ws;
  const size_t hBytes = (size_t)HROWS * H_ * 4;           // 294,912
  unsigned* cnt = (unsigned*)ws;                          // 4 KB
  unsigned* hA  = (unsigned*)(ws + 4096);
  unsigned* hB  = (unsigned*)(ws + 4096 + hBytes);
  unsigned* Y   = (unsigned*)(ws + 4096 + 2 * hBytes);    // 16 MB
  // total 17,371,136 B  (<= 18,088,960 proven available in round 3)

  (void)hipMemsetAsync(d_ws, 0, 4096, stream);   // zero barrier counters

  void* args[] = {&x, &Wih0, &Whh0, &bih0, &bhh0, &Whr0,
                  &Wihs, &Whhs, &bihs, &bhhs, &Whrs,
                  &out, &Y, &hA, &hB, &cnt};
  hipError_t e = hipLaunchCooperativeKernel((void*)lstm_kernel, dim3(NWG),
                                            dim3(NTHR), args, 0, stream);
  if (e != hipSuccess) {
    // Plain launch fallback: the grid barrier is hand-rolled; 128 WGs on
    // 256 CUs are co-resident under a normal launch too (1 WG/CU fits).
    lstm_kernel<<<dim3(NWG), dim3(NTHR), 0, stream>>>(
        x, Wih0, Whh0, bih0, bhh0, Whr0, Wihs, Whhs, bihs, bhhs, Whrs,
        out, Y, hA, hB, cnt);
  }
}